// Round 1
// baseline (420.421 us; speedup 1.0000x reference)
//
#include <hip/hip_runtime.h>
#include <stdint.h>

#define DI __device__ __forceinline__

typedef unsigned short u16;
typedef unsigned int   u32;
typedef __attribute__((ext_vector_type(8))) short short8;
typedef __attribute__((ext_vector_type(4))) float f32x4;
typedef __attribute__((ext_vector_type(4))) u32   u32x4;

// ---- constants (problem shape hardcoded) ----
// B=2, S=2048, HID=2048, HQ=16, HKV=8, D=128

DI u16 f2bf(float f) {
    u32 u = __float_as_uint(f);
    u32 r = u + 0x7fff + ((u >> 16) & 1);   // RNE
    return (u16)(r >> 16);
}
DI float bf2f(u16 h) { return __uint_as_float(((u32)h) << 16); }

DI f32x4 mfma16(short8 a, short8 b, f32x4 c) {
    return __builtin_amdgcn_mfma_f32_16x16x32_bf16(a, b, c, 0, 0, 0);
}

DI void gload_lds16(const void* g, void* l) {
    __builtin_amdgcn_global_load_lds(
        (const __attribute__((address_space(1))) void*)g,
        (__attribute__((address_space(3))) void*)l, 16, 0, 0);
}

// ---------------- convert x f32 -> bf16 ----------------
__global__ __launch_bounds__(256) void cvt_x(const float* __restrict__ x,
                                             u16* __restrict__ o, int n4) {
    int i = blockIdx.x * 256 + threadIdx.x;
    if (i >= n4) return;
    float4 v = *(const float4*)(x + (size_t)i * 4);
    u32 p0 = (u32)f2bf(v.x) | ((u32)f2bf(v.y) << 16);
    u32 p1 = (u32)f2bf(v.z) | ((u32)f2bf(v.w) << 16);
    uint2 p; p.x = p0; p.y = p1;
    *(uint2*)(o + (size_t)i * 4) = p;
}

// ---------------- W [K][N] f32 -> WT [N][K] bf16 ----------------
__global__ __launch_bounds__(256) void transpose_cvt(const float* __restrict__ W,
                                                     u16* __restrict__ WT,
                                                     int K, int N) {
    __shared__ u16 tl[64][65];
    int tx = threadIdx.x & 15, ty = threadIdx.x >> 4;
    int tc = blockIdx.x * 64, tr = blockIdx.y * 64;
#pragma unroll
    for (int i = 0; i < 4; i++) {
        int r = tr + ty + i * 16;
        float4 v = *(const float4*)&W[(size_t)r * N + tc + tx * 4];
        tl[tx*4+0][ty+i*16] = f2bf(v.x);
        tl[tx*4+1][ty+i*16] = f2bf(v.y);
        tl[tx*4+2][ty+i*16] = f2bf(v.z);
        tl[tx*4+3][ty+i*16] = f2bf(v.w);
    }
    __syncthreads();
#pragma unroll
    for (int i = 0; i < 4; i++) {
        int n = tc + ty + i * 16;
        uint2 p;
        p.x = (u32)tl[ty+i*16][tx*4+0] | ((u32)tl[ty+i*16][tx*4+1] << 16);
        p.y = (u32)tl[ty+i*16][tx*4+2] | ((u32)tl[ty+i*16][tx*4+3] << 16);
        *(uint2*)&WT[(size_t)n * K + tr + tx * 4] = p;
    }
}

// ---------------- RoPE in-place on bf16 [tok][H*128] ----------------
__global__ __launch_bounds__(256) void rope_kernel(u16* __restrict__ buf,
                                                   const float* __restrict__ fc,
                                                   const float* __restrict__ fs,
                                                   int H, int tokshift, int total) {
    int idx = blockIdx.x * 256 + threadIdx.x;
    if (idx >= total) return;
    int tok = idx >> tokshift;
    int rem = idx & ((1 << tokshift) - 1);
    int h = rem >> 6, j = rem & 63;
    int s = tok & 2047;
    size_t a = ((size_t)tok * H + h) * 128 + 2 * j;
    u32 v = *(u32*)(buf + a);
    float re = bf2f((u16)(v & 0xffff));
    float im = bf2f((u16)(v >> 16));
    float c = fc[s * 64 + j], sn = fs[s * 64 + j];
    u32 o = (u32)f2bf(re * c - im * sn) | ((u32)f2bf(re * sn + im * c) << 16);
    *(u32*)(buf + a) = o;
}

// ---------------- m97-style bf16 GEMM, A[M][K] * BT[N][K] ----------------
// MODE 0: bf16 row-major store; MODE 1: V_T scatter store; MODE 2: f32 store
template <int MODE>
__global__ __launch_bounds__(256) void gemm_bt(const u16* __restrict__ A,
                                               const u16* __restrict__ BT,
                                               u16* __restrict__ Ob,
                                               float* __restrict__ Of,
                                               int M, int N, int K) {
    __shared__ u16 As[128 * 32];
    __shared__ u16 Bs[128 * 32];
    const int tid = threadIdx.x;
    const int w = tid >> 6, l = tid & 63;
    const int m0 = blockIdx.y * 128, n0 = blockIdx.x * 128;
    const int wr = w >> 1, wc = w & 1;
    const int l15 = l & 15, lh = l >> 4;

    const f32x4 fz = {0.f, 0.f, 0.f, 0.f};
    f32x4 acc[4][4];
#pragma unroll
    for (int m = 0; m < 4; m++)
#pragma unroll
        for (int n = 0; n < 4; n++) acc[m][n] = fz;

    const int rowA = w * 32 + (l >> 2);   // + c*16
    const int colb = (l & 3) * 8;         // elems

    for (int k0 = 0; k0 < K; k0 += 32) {
        __syncthreads();
#pragma unroll
        for (int c = 0; c < 2; c++) {
            gload_lds16(A  + (size_t)(m0 + rowA + c * 16) * K + k0 + colb,
                        &As[w * 1024 + c * 512]);
            gload_lds16(BT + (size_t)(n0 + rowA + c * 16) * K + k0 + colb,
                        &Bs[w * 1024 + c * 512]);
        }
        __syncthreads();
        short8 af[4], bfr[4];
#pragma unroll
        for (int m = 0; m < 4; m++)
            af[m] = *(const short8*)&As[(wr * 64 + m * 16 + l15) * 32 + lh * 8];
#pragma unroll
        for (int n = 0; n < 4; n++)
            bfr[n] = *(const short8*)&Bs[(wc * 64 + n * 16 + l15) * 32 + lh * 8];
#pragma unroll
        for (int m = 0; m < 4; m++)
#pragma unroll
            for (int n = 0; n < 4; n++)
                acc[m][n] = mfma16(af[m], bfr[n], acc[m][n]);
    }

    const int rbase = m0 + wr * 64 + lh * 4;  // + m*16 + j
    const int cbase = n0 + wc * 64 + l15;     // + n*16

    if (MODE == 0) {
#pragma unroll
        for (int m = 0; m < 4; m++)
#pragma unroll
            for (int j = 0; j < 4; j++) {
                size_t ro = (size_t)(rbase + m * 16 + j) * N + cbase;
#pragma unroll
                for (int n = 0; n < 4; n++)
                    Ob[ro + n * 16] = f2bf(acc[m][n][j]);
            }
    } else if (MODE == 2) {
#pragma unroll
        for (int m = 0; m < 4; m++)
#pragma unroll
            for (int j = 0; j < 4; j++) {
                size_t ro = (size_t)(rbase + m * 16 + j) * N + cbase;
#pragma unroll
                for (int n = 0; n < 4; n++)
                    Of[ro + n * 16] = acc[m][n][j];
            }
    } else {  // MODE 1: V_T[b][h2][d][s] bf16, 4 consecutive s per lane
#pragma unroll
        for (int m = 0; m < 4; m++)
#pragma unroll
            for (int n = 0; n < 4; n++) {
                int r = rbase + m * 16;          // token of j=0
                int c = cbase + n * 16;
                int bb = r >> 11, s = r & 2047;
                int h2 = c >> 7, d = c & 127;
                uint2 v;
                v.x = (u32)f2bf(acc[m][n][0]) | ((u32)f2bf(acc[m][n][1]) << 16);
                v.y = (u32)f2bf(acc[m][n][2]) | ((u32)f2bf(acc[m][n][3]) << 16);
                *(uint2*)(Ob + (size_t)((bb * 8 + h2) * 128 + d) * 2048 + s) = v;
            }
    }
}

// ---------------- flash attention (non-causal, GQA) ----------------
// grid (32 qtiles, 32 b*h); block 256 = 4 waves; wave owns 16 q rows.
__global__ __launch_bounds__(256) void attn_kernel(const u16* __restrict__ Q,
                                                   const u16* __restrict__ Kg,
                                                   const u16* __restrict__ Vg,
                                                   u16* __restrict__ O) {
    __shared__ u16 Ks[64 * 136];   // [key][128] pad->136
    __shared__ u16 Vs[128 * 72];   // V^T [d][64key] pad->72
    __shared__ u16 Ps[4][16 * 72]; // per-wave P [q16][64key] pad->72
    const int tid = threadIdx.x;
    const int w = tid >> 6, l = tid & 63;
    const int qt = blockIdx.x, bh = blockIdx.y;
    const int b = bh >> 4, h = bh & 15, h2 = h >> 1;
    const int l15 = l & 15, lh = l >> 4;

    short8 qf[4];
    {
        const int qrow = qt * 64 + w * 16 + l15;
        const u16* qp = Q + ((size_t)(b * 2048 + qrow)) * 2048 + h * 128 + lh * 8;
#pragma unroll
        for (int ks = 0; ks < 4; ks++) qf[ks] = *(const short8*)(qp + ks * 32);
    }
    const f32x4 fz = {0.f, 0.f, 0.f, 0.f};
    f32x4 o[8];
#pragma unroll
    for (int n = 0; n < 8; n++) o[n] = fz;
    float mrow[4] = {-1e30f, -1e30f, -1e30f, -1e30f};
    float lrow[4] = {0.f, 0.f, 0.f, 0.f};

    for (int t = 0; t < 32; t++) {
        __syncthreads();
        {
            const size_t kgb = ((size_t)(b * 2048 + t * 64)) * 1024 + h2 * 128;
#pragma unroll
            for (int i = 0; i < 4; i++) {
                int r = i * 16 + (tid >> 4);
                int cb = (tid & 15) * 8;
                u32x4 v = *(const u32x4*)(Kg + kgb + (size_t)r * 1024 + cb);
                *(u32x4*)&Ks[r * 136 + cb] = v;
            }
            const size_t vgb = ((size_t)((b * 8 + h2) * 128)) * 2048 + t * 64;
#pragma unroll
            for (int i = 0; i < 4; i++) {
                int d = i * 32 + (tid >> 3);
                int kb2 = (tid & 7) * 8;
                u32x4 v = *(const u32x4*)(Vg + vgb + (size_t)d * 2048 + kb2);
                *(u32x4*)&Vs[d * 72 + kb2] = v;
            }
        }
        __syncthreads();

        f32x4 s[4];
#pragma unroll
        for (int ct = 0; ct < 4; ct++) {
            s[ct] = fz;
#pragma unroll
            for (int ks = 0; ks < 4; ks++) {
                short8 kf = *(const short8*)&Ks[(ct * 16 + l15) * 136 + ks * 32 + lh * 8];
                s[ct] = mfma16(qf[ks], kf, s[ct]);
            }
        }

        const float sc = 0.08838834764831845f;  // 1/sqrt(128)
#pragma unroll
        for (int r = 0; r < 4; r++) {
            float v0 = s[0][r] * sc, v1 = s[1][r] * sc,
                  v2 = s[2][r] * sc, v3 = s[3][r] * sc;
            float mx = fmaxf(fmaxf(v0, v1), fmaxf(v2, v3));
            mx = fmaxf(mx, __shfl_xor(mx, 1));
            mx = fmaxf(mx, __shfl_xor(mx, 2));
            mx = fmaxf(mx, __shfl_xor(mx, 4));
            mx = fmaxf(mx, __shfl_xor(mx, 8));
            float mnew = fmaxf(mrow[r], mx);
            float fsc = __expf(mrow[r] - mnew);
            mrow[r] = mnew;
            float p0 = __expf(v0 - mnew), p1 = __expf(v1 - mnew),
                  p2 = __expf(v2 - mnew), p3 = __expf(v3 - mnew);
            float ps = p0 + p1 + p2 + p3;
            ps += __shfl_xor(ps, 1); ps += __shfl_xor(ps, 2);
            ps += __shfl_xor(ps, 4); ps += __shfl_xor(ps, 8);
            lrow[r] = lrow[r] * fsc + ps;
#pragma unroll
            for (int n = 0; n < 8; n++) o[n][r] *= fsc;
            u16* pr = &Ps[w][(lh * 4 + r) * 72 + l15];
            pr[0]  = f2bf(p0); pr[16] = f2bf(p1);
            pr[32] = f2bf(p2); pr[48] = f2bf(p3);
        }
        __syncthreads();  // guarantee P writes visible/ordered before vector reads

#pragma unroll
        for (int ks2 = 0; ks2 < 2; ks2++) {
            short8 pf = *(const short8*)&Ps[w][l15 * 72 + ks2 * 32 + lh * 8];
#pragma unroll
            for (int n = 0; n < 8; n++) {
                short8 vf = *(const short8*)&Vs[(n * 16 + l15) * 72 + ks2 * 32 + lh * 8];
                o[n] = mfma16(pf, vf, o[n]);
            }
        }
    }

    float linv[4];
#pragma unroll
    for (int r = 0; r < 4; r++) linv[r] = 1.0f / lrow[r];
    const size_t ob = ((size_t)(b * 2048 + qt * 64 + w * 16 + lh * 4)) * 2048 + h * 128 + l15;
#pragma unroll
    for (int n = 0; n < 8; n++)
#pragma unroll
        for (int r = 0; r < 4; r++)
            O[ob + (size_t)r * 2048 + n * 16] = f2bf(o[n][r] * linv[r]);
}

// ---------------- launch ----------------
extern "C" void kernel_launch(void* const* d_in, const int* in_sizes, int n_in,
                              void* d_out, int out_size, void* d_ws, size_t ws_size,
                              hipStream_t stream) {
    const float* x  = (const float*)d_in[0];
    const float* Wq = (const float*)d_in[1];
    const float* Wk = (const float*)d_in[2];
    const float* Wv = (const float*)d_in[3];
    const float* Wo = (const float*)d_in[4];
    const float* fc = (const float*)d_in[5];
    const float* fs = (const float*)d_in[6];
    float* out = (float*)d_out;

    uint8_t* ws = (uint8_t*)d_ws;
    u16* xb  = (u16*)(ws + 0);          // 16.8 MB  (aliased as attn_out later)
    u16* wqT = (u16*)(ws + 16777216);   // 8.4 MB
    u16* wkT = (u16*)(ws + 25165824);   // 4.2 MB
    u16* wvT = (u16*)(ws + 29360128);   // 4.2 MB
    u16* woT = (u16*)(ws + 33554432);   // 8.4 MB
    u16* qb  = (u16*)(ws + 41943040);   // 16.8 MB
    u16* kb  = (u16*)(ws + 58720256);   // 8.4 MB
    u16* vT  = (u16*)(ws + 67108864);   // 8.4 MB   total 75.5 MB
    u16* ao  = xb;                      // alias: x_bf16 dead after V gemm

    cvt_x<<<dim3(8192), dim3(256), 0, stream>>>(x, xb, 2097152);
    transpose_cvt<<<dim3(32, 32), dim3(256), 0, stream>>>(Wq, wqT, 2048, 2048);
    transpose_cvt<<<dim3(16, 32), dim3(256), 0, stream>>>(Wk, wkT, 2048, 1024);
    transpose_cvt<<<dim3(16, 32), dim3(256), 0, stream>>>(Wv, wvT, 2048, 1024);
    transpose_cvt<<<dim3(32, 32), dim3(256), 0, stream>>>(Wo, woT, 2048, 2048);

    gemm_bt<0><<<dim3(16, 32), dim3(256), 0, stream>>>(xb, wqT, qb, nullptr, 4096, 2048, 2048);
    gemm_bt<0><<<dim3(8, 32),  dim3(256), 0, stream>>>(xb, wkT, kb, nullptr, 4096, 1024, 2048);
    gemm_bt<1><<<dim3(8, 32),  dim3(256), 0, stream>>>(xb, wvT, vT, nullptr, 4096, 1024, 2048);

    rope_kernel<<<dim3(16384), dim3(256), 0, stream>>>(qb, fc, fs, 16, 10, 4194304);
    rope_kernel<<<dim3(8192),  dim3(256), 0, stream>>>(kb, fc, fs, 8, 9, 2097152);

    attn_kernel<<<dim3(32, 32), dim3(256), 0, stream>>>(qb, kb, vT, ao);

    gemm_bt<2><<<dim3(16, 32), dim3(256), 0, stream>>>(ao, woT, nullptr, out, 4096, 2048, 2048);
}